// Round 1
// baseline (283.785 us; speedup 1.0000x reference)
//
#include <hip/hip_runtime.h>
#include <hip/hip_bf16.h>
#include <math.h>

#define N_REFLNS 2000000
#define N_IMAGES 8192
#define N_RAC    1000000
#define MC       8
#define D_META   16
#define HIDDEN   32
#define LOG_2PI  1.8378770664093453f
#define LOG2E    1.44269504089f
#define LN2      0.69314718056f

#define NBLK_Z   ((N_RAC + 255) / 256)   // 3907 blocks for k_z_kl

// Workspace layout (bytes):
//   [0, 32768)            img_sum   (8192 f32)
//   [32768, 65536)        img_cnt   (8192 f32)
//   [65536, 65536+4*NBLK_Z) kl_part (per-block KL partials, no atomics)
//   [131072, 131072+32e6) zT        (N_RAC x MC f32, transposed z for 32B gathers)

typedef __attribute__((ext_vector_type(4)))  float fv4;
typedef __attribute__((ext_vector_type(8)))  short bf16x8;
typedef __attribute__((ext_vector_type(4)))  float f32x4;
typedef __attribute__((ext_vector_type(16))) float f32x16;

#define MFMA16(A, B, C) __builtin_amdgcn_mfma_f32_16x16x32_bf16(A, B, C, 0, 0, 0)
#define MFMA32(A, B, C) __builtin_amdgcn_mfma_f32_32x32x16_bf16(A, B, C, 0, 0, 0)

union B8 { bf16x8 v; unsigned u[4]; };

__device__ __forceinline__ fv4 nt_load4(const float* p) {
    return __builtin_nontemporal_load((const fv4*)p);
}

// Dekker split: hi = trunc-to-bf16, lo = trunc(x - hi). rel err ~2^-17.
__device__ __forceinline__ void split_hilo(const float* x, bf16x8& hi, bf16x8& lo) {
    B8 h, l;
    #pragma unroll
    for (int p = 0; p < 4; p++) {
        unsigned u0 = __float_as_uint(x[2 * p]);
        unsigned u1 = __float_as_uint(x[2 * p + 1]);
        unsigned hf0 = u0 & 0xFFFF0000u;
        unsigned hf1 = u1 & 0xFFFF0000u;
        h.u[p] = (u0 >> 16) | hf1;
        float d0 = x[2 * p]     - __uint_as_float(hf0);
        float d1 = x[2 * p + 1] - __uint_as_float(hf1);
        l.u[p] = (__float_as_uint(d0) >> 16) | (__float_as_uint(d1) & 0xFFFF0000u);
    }
    hi = h.v; lo = l.v;
}

// RNE pack via packed hw conversion (v_cvt_pk_bf16_f32 on gfx950).
__device__ __forceinline__ bf16x8 pack8_rne(float4 a0, float4 a1) {
    B8 r;
    __hip_bfloat162 t0 = __float22bfloat162_rn(make_float2(a0.x, a0.y));
    __hip_bfloat162 t1 = __float22bfloat162_rn(make_float2(a0.z, a0.w));
    __hip_bfloat162 t2 = __float22bfloat162_rn(make_float2(a1.x, a1.y));
    __hip_bfloat162 t3 = __float22bfloat162_rn(make_float2(a1.z, a1.w));
    r.u[0] = reinterpret_cast<unsigned&>(t0);
    r.u[1] = reinterpret_cast<unsigned&>(t1);
    r.u[2] = reinterpret_cast<unsigned&>(t2);
    r.u[3] = reinterpret_cast<unsigned&>(t3);
    return r.v;
}

// softplus via native v_exp/v_log (log2 domain)
__device__ __forceinline__ float softplus_fast(float x) {
    float t = __builtin_amdgcn_exp2f(-fabsf(x) * LOG2E);
    return fmaxf(x, 0.0f) + LN2 * __builtin_amdgcn_logf(1.0f + t);
}

// ---------------- Kernel A: zT + KL, 1 RAC entry per thread ----------------
// 1 entry/thread gives 32B-contiguous zT stores (lane stride 32B, full-line
// coalescing) instead of the old 16B writes at 128B lane stride.
// Also: zeroes img_sum/img_cnt (blocks 0..63) so the hipMemsetAsync dispatch
// disappears, and writes per-block KL partials (no atomic, no zero needed).
__global__ __launch_bounds__(256) void k_z_kl(
    const float* __restrict__ q_loc,
    const float* __restrict__ q_log_scale,
    const float* __restrict__ eps,
    float* __restrict__ zT,          // may be null (fallback)
    float* __restrict__ kl_part,     // NBLK_Z partials
    float* __restrict__ img_zero)    // img_sum base: 16384 f32 zeroed by blocks 0..63
{
    if (blockIdx.x < 64) {
        img_zero[blockIdx.x * 256 + threadIdx.x] = 0.0f;
    }
    int t = blockIdx.x * 256 + threadIdx.x;
    float kl = 0.0f;
    if (t < N_RAC) {
        float ql  = __builtin_nontemporal_load(q_loc + t);
        float qls = __builtin_nontemporal_load(q_log_scale + t);
        float qs  = __builtin_amdgcn_exp2f(qls * LOG2E);
        kl = 0.5f * (qs * qs + ql * ql - 1.0f) - qls;
        if (zT) {
            float zr[MC];
            #pragma unroll
            for (int s = 0; s < MC; s++) {
                float e = __builtin_nontemporal_load(eps + (size_t)s * N_RAC + t);
                zr[s] = fmaf(qs, e, ql);
            }
            fv4* dst = (fv4*)(zT + (size_t)t * MC);
            fv4 z0 = {zr[0], zr[1], zr[2], zr[3]};
            fv4 z1 = {zr[4], zr[5], zr[6], zr[7]};
            dst[0] = z0;   // cached store: warms L2 for k_main's gather
            dst[1] = z1;
        }
    }
    __shared__ float sred[256];
    sred[threadIdx.x] = kl;
    __syncthreads();
    #pragma unroll
    for (int s = 128; s > 0; s >>= 1) {
        if (threadIdx.x < s) sred[threadIdx.x] += sred[threadIdx.x + s];
        __syncthreads();
    }
    if (threadIdx.x == 0) kl_part[blockIdx.x] = sred[0];
}

// ---------------- Kernel B: MFMA MLP + likelihood -----------------------------
// Block = 4 waves; each wave owns 64 reflections = 2 supertiles of 32 rows.
// Per-lane epilogue globals (miller->zT gather, iobs, sig, image_id) are issued
// at wave start so their latency overlaps the MFMA MLP. Per-image reduction is
// a wave-level segmented scan (shfl, no barriers); run tails atomicAdd.
// All single-use streams are non-temporal so the 32MB zT table keeps L2.
template <bool HAS_Z>
__global__ __launch_bounds__(256) void k_main(
    const float* __restrict__ metadata,
    const float* __restrict__ W1, const float* __restrict__ b1,
    const float* __restrict__ W2, const float* __restrict__ b2,
    const float* __restrict__ iobs, const float* __restrict__ sigiobs,
    const int* __restrict__ image_id, const int* __restrict__ miller_id,
    const float* __restrict__ zT,
    const float* __restrict__ q_loc, const float* __restrict__ q_log_scale,
    const float* __restrict__ eps,
    float* __restrict__ out_ipred,
    float* __restrict__ img_sum, float* __restrict__ img_cnt)
{
    __shared__ __align__(16) float sH[4][32 * 36];   // per-wave H supertile
    __shared__ __align__(16) float sL[4][4 * 160];   // per-wave logits, 4 tiles

    int tid  = threadIdx.x;
    int wave = tid >> 6;
    int lane = tid & 63;
    int n31  = lane & 31;   // 32x32: A-row (m) / B-col (n) / D-col
    int kh   = lane >> 5;   // 32x32: k-half (k = kh*8 + j)
    int q    = lane >> 4;   // 16x16: quad 0..3
    int c16  = lane & 15;   // 16x16: A-row / D-col

    int base_w = blockIdx.x * 256 + wave * 64;

    // ---- EARLY: per-lane epilogue globals + zT gather (overlap with MLP) ----
    int n = base_w + lane;
    bool valid = (n < N_REFLNS);
    int nc = valid ? n : (N_REFLNS - 1);
    int m    = __builtin_nontemporal_load(miller_id + nc);
    float io = __builtin_nontemporal_load(iobs + nc);
    float sg = __builtin_nontemporal_load(sigiobs + nc);
    int img  = __builtin_nontemporal_load(image_id + nc);
    float f[MC];
    if (HAS_Z) {
        const float4* zp = (const float4*)(zT + (size_t)m * MC);  // cached
        float4 z0 = zp[0], z1 = zp[1];
        f[0] = z0.x; f[1] = z0.y; f[2] = z0.z; f[3] = z0.w;
        f[4] = z1.x; f[5] = z1.y; f[6] = z1.z; f[7] = z1.w;
    } else {
        float qlv = q_loc[m];
        float qsv = expf(q_log_scale[m]);
        #pragma unroll
        for (int s = 0; s < MC; s++) f[s] = qlv + qsv * eps[(size_t)s * N_RAC + m];
    }

    // ---- EARLY: both supertiles' A rows (ILP across the K-chain) ----
    fv4 a_m[2][2];
    #pragma unroll
    for (int st = 0; st < 2; st++) {
        int r = base_w + st * 32 + n31;
        if (r > N_REFLNS - 1) r = N_REFLNS - 1;
        const float* mp = metadata + (size_t)r * D_META + kh * 8;
        a_m[st][0] = nt_load4(mp);
        a_m[st][1] = nt_load4(mp + 4);
    }

    // ---- weight fragments ----
    bf16x8 W1h, W1l;   // B[k][n], k=kh*8+j, n=n31
    {
        float tmp[8];
        #pragma unroll
        for (int j = 0; j < 8; j++) tmp[j] = W1[(kh * 8 + j) * HIDDEN + n31];
        split_hilo(tmp, W1h, W1l);
    }
    float b1v = b1[n31];
    bf16x8 W2h, W2l;   // B[k][n], k=q*8+j, n=c16
    {
        float tmp[8];
        #pragma unroll
        for (int j = 0; j < 8; j++) tmp[j] = (c16 < MC) ? W2[(q * 8 + j) * MC + c16] : 0.0f;
        split_hilo(tmp, W2h, W2l);
    }
    float b2v = (c16 < MC) ? b2[c16] : 0.0f;

    float* Hb = &sH[wave][0];
    float* Lb = &sL[wave][0];

    #pragma unroll
    for (int st = 0; st < 2; st++) {
        // ---- A-frag split ----
        fv4 a0 = a_m[st][0], a1 = a_m[st][1];
        float av[8] = {a0[0], a0[1], a0[2], a0[3], a1[0], a1[1], a1[2], a1[3]};
        bf16x8 Ah, Al;
        split_hilo(av, Ah, Al);

        // ---- layer 1: one 32x32 tile, 3-term hi/lo ----
        f32x16 cc;
        #pragma unroll
        for (int i = 0; i < 16; i++) cc[i] = b1v;
        cc = MFMA32(Al, W1h, cc);
        cc = MFMA32(Ah, W1l, cc);
        cc = MFMA32(Ah, W1h, cc);
        #pragma unroll
        for (int i = 0; i < 16; i++) {
            int row = (i & 3) + 8 * (i >> 2) + 4 * kh;
            Hb[row * 36 + n31] = fmaxf(cc[i], 0.0f);
        }

        // ---- layer 2: two 16-row tiles (same-wave LDS ordering) ----
        #pragma unroll
        for (int t2 = 0; t2 < 2; t2++) {
            const float4* hp = (const float4*)(Hb + (t2 * 16 + c16) * 36 + q * 8);
            bf16x8 Hh = pack8_rne(hp[0], hp[1]);
            f32x4 c2 = {b2v, b2v, b2v, b2v};
            c2 = MFMA16(Hh, W2l, c2);
            c2 = MFMA16(Hh, W2h, c2);
            if (c16 < MC) {
                #pragma unroll
                for (int rr = 0; rr < 4; rr++) {
                    Lb[(st * 2 + t2) * 160 + (q * 4 + rr) * 10 + c16] = c2[rr];
                }
            }
        }
    }

    // ---- epilogue: one reflection per lane ----
    float ll_sum = 0.0f;
    {
        float lg[MC];
        const float2* lp = (const float2*)(Lb + (lane >> 4) * 160 + c16 * 10);
        float2 p0 = lp[0], p1 = lp[1], p2 = lp[2], p3 = lp[3];
        lg[0] = p0.x; lg[1] = p0.y; lg[2] = p1.x; lg[3] = p1.y;
        lg[4] = p2.x; lg[5] = p2.y; lg[6] = p3.x; lg[7] = p3.y;

        float sum_ip = 0.0f, sum_d2 = 0.0f;
        #pragma unroll
        for (int s = 0; s < MC; s++) {
            float sc = softplus_fast(lg[s]);
            float ip = f[s] * f[s] * sc;
            sum_ip += ip;
            float d = ip - io;
            sum_d2 = fmaf(d, d, sum_d2);
        }
        float inv = __builtin_amdgcn_rcpf(sg);
        if (valid) __builtin_nontemporal_store(sum_ip * (1.0f / MC), out_ipred + n);
        ll_sum = -0.5f * sum_d2 * inv * inv
                 - (float)MC * (0.5f * LOG_2PI)
                 - (float)MC * (LN2 * __builtin_amdgcn_logf(sg));
    }

    // ---- wave-level segmented inclusive scan over sorted image ids ----
    float v = valid ? ll_sum : 0.0f;
    float c = valid ? 1.0f : 0.0f;
    int   id = img;
    #pragma unroll
    for (int d = 1; d < 64; d <<= 1) {
        float pv = __shfl_up(v, d, 64);
        float pc = __shfl_up(c, d, 64);
        int  pid = __shfl_up(id, d, 64);
        if (lane >= d && pid == id) { v += pv; c += pc; }
    }
    int nid = __shfl_down(id, 1, 64);
    bool tail = (lane == 63) || (nid != id);
    if (valid && tail && c > 0.0f) {
        atomicAdd(&img_sum[id], v);
        atomicAdd(&img_cnt[id], c);
    }
}

// ---------------- Kernel C: finalize scalars ----------------
__global__ __launch_bounds__(256) void k_final(
    const float* __restrict__ img_sum,
    const float* __restrict__ img_cnt,
    const float* __restrict__ kl_part,
    float* __restrict__ out)
{
    __shared__ float s1[256], s2[256];
    float acc = 0.0f, klacc = 0.0f;
    for (int i = threadIdx.x; i < N_IMAGES; i += 256) {
        acc += img_sum[i] / fmaxf(img_cnt[i], 1.0f);
    }
    for (int i = threadIdx.x; i < NBLK_Z; i += 256) {
        klacc += kl_part[i];
    }
    s1[threadIdx.x] = acc;
    s2[threadIdx.x] = klacc;
    __syncthreads();
    #pragma unroll
    for (int s = 128; s > 0; s >>= 1) {
        if (threadIdx.x < s) {
            s1[threadIdx.x] += s1[threadIdx.x + s];
            s2[threadIdx.x] += s2[threadIdx.x + s];
        }
        __syncthreads();
    }
    if (threadIdx.x == 0) {
        float mean_ll = s1[0] / ((float)MC * (float)N_IMAGES);
        out[N_REFLNS]     = -mean_ll;
        out[N_REFLNS + 1] = s2[0] * (1.0f / (float)N_RAC);
    }
}

extern "C" void kernel_launch(void* const* d_in, const int* in_sizes, int n_in,
                              void* d_out, int out_size, void* d_ws, size_t ws_size,
                              hipStream_t stream) {
    const float* q_loc       = (const float*)d_in[0];
    const float* q_log_scale = (const float*)d_in[1];
    const float* eps         = (const float*)d_in[2];
    const float* metadata    = (const float*)d_in[3];
    const float* W1          = (const float*)d_in[4];
    const float* b1          = (const float*)d_in[5];
    const float* W2          = (const float*)d_in[6];
    const float* b2          = (const float*)d_in[7];
    const float* iobs        = (const float*)d_in[8];
    const float* sigiobs     = (const float*)d_in[9];
    const int*   image_id    = (const int*)d_in[10];
    const int*   miller_id   = (const int*)d_in[11];
    float* out = (float*)d_out;

    char* ws = (char*)d_ws;
    float* img_sum = (float*)ws;                 // 8192
    float* img_cnt = img_sum + N_IMAGES;         // 8192
    float* kl_part = img_cnt + N_IMAGES;         // NBLK_Z partials
    const size_t z_off = 131072;                 // bytes; clear of kl_part
    bool has_z = (ws_size >= z_off + (size_t)N_RAC * MC * sizeof(float));
    float* zT = has_z ? (float*)(ws + z_off) : nullptr;

    // no hipMemsetAsync: k_z_kl zeroes img_sum/img_cnt (blocks 0..63) and
    // kl_part is written unconditionally by every block.
    k_z_kl<<<NBLK_Z, 256, 0, stream>>>(q_loc, q_log_scale, eps, zT, kl_part, img_sum);

    if (has_z) {
        k_main<true><<<(N_REFLNS + 255) / 256, 256, 0, stream>>>(
            metadata, W1, b1, W2, b2, iobs, sigiobs, image_id, miller_id,
            zT, q_loc, q_log_scale, eps, out, img_sum, img_cnt);
    } else {
        k_main<false><<<(N_REFLNS + 255) / 256, 256, 0, stream>>>(
            metadata, W1, b1, W2, b2, iobs, sigiobs, image_id, miller_id,
            nullptr, q_loc, q_log_scale, eps, out, img_sum, img_cnt);
    }

    k_final<<<1, 256, 0, stream>>>(img_sum, img_cnt, kl_part, out);
}